// Round 7
// baseline (53.028 us; speedup 1.0000x reference)
//
#include <hip/hip_runtime.h>
#include <hip/hip_bf16.h>

#define NCLS 200
#define NPADP 224       // padded proto rows = 14 x 16
#define NTW 7           // class tiles per wave (2 N-waves x 7 x 16 = 224)
#define DIM 512
#define NSAMP 32768
#define NSEG 8          // psum sample segments
#define CAP 32          // per-wave list capacity (512-sample segment, expect ~2.6)
#define BM 64           // sample rows per block
#define NPASS 4         // K quarters
#define KQ 128          // k per pass

typedef __attribute__((ext_vector_type(4))) float f32x4;
typedef __attribute__((ext_vector_type(4))) int   i32x4;
typedef __attribute__((ext_vector_type(8))) short bf16x8;

__device__ inline short bf16s(float x) {
  __hip_bfloat16 h = __float2bfloat16(x);
  return *reinterpret_cast<short*>(&h);
}

__device__ inline bf16x8 pack8(f32x4 a, f32x4 b) {
  bf16x8 r;
  r[0] = bf16s(a[0]); r[1] = bf16s(a[1]); r[2] = bf16s(a[2]); r[3] = bf16s(a[3]);
  r[4] = bf16s(b[0]); r[5] = bf16s(b[1]); r[6] = bf16s(b[2]); r[7] = bf16s(b[3]);
  return r;
}

__device__ inline float sumsq(f32x4 a) {
  return a[0]*a[0] + a[1]*a[1] + a[2]*a[2] + a[3]*a[3];
}

// Raw barrier: drain only LDS ops; global loads stay in flight across it.
__device__ inline void bar_lgkm() {
  asm volatile("s_waitcnt lgkmcnt(0)" ::: "memory");
  __builtin_amdgcn_s_barrier();
}

// ---------------- Kernel 1a: per-(class, segment) partial sums -----------------
__global__ __launch_bounds__(512) void k_psum(
    const float* __restrict__ feat, const int* __restrict__ labels,
    float* __restrict__ psum, int* __restrict__ pcnt)
{
  const int bx = blockIdx.x;
  const int c = bx >> 3, s = bx & 7;
  const int tid = threadIdx.x;
  const int lane = tid & 63;
  const int w = tid >> 6;

  __shared__ int   lists[8][CAP];
  __shared__ int   cnts[8];
  __shared__ float partial[8][DIM];

  int cnt = 0;
  const int segbase = s * (NSAMP / NSEG) + w * (NSAMP / NSEG / 8);
  #pragma unroll
  for (int i = 0; i < 2; ++i) {                           // 2 x 256 samples
    const int base = segbase + i * 256 + lane * 4;
    const i32x4 lab4 = *(const i32x4*)(labels + base);
    #pragma unroll
    for (int u = 0; u < 4; ++u) {
      const bool m = (lab4[u] == c);
      const unsigned long long bal = __ballot(m);
      if (m) {
        const int pos = cnt + __popcll(bal & ((1ull << lane) - 1ull));
        if (pos < CAP) lists[w][pos] = base + u;
      }
      cnt += __popcll(bal);
    }
  }
  if (cnt > CAP) cnt = CAP;
  if (lane == 0) cnts[w] = cnt;

  float aE[8], aO[8];
  #pragma unroll
  for (int q = 0; q < 8; ++q) { aE[q] = 0.f; aO[q] = 0.f; }
  int j = 0;
  for (; j + 2 <= cnt; j += 2) {
    const int r0 = lists[w][j], r1 = lists[w][j + 1];
    const f32x4 a0 = *(const f32x4*)(feat + (size_t)r0 * DIM + lane * 8);
    const f32x4 b0 = *(const f32x4*)(feat + (size_t)r0 * DIM + lane * 8 + 4);
    const f32x4 a1 = *(const f32x4*)(feat + (size_t)r1 * DIM + lane * 8);
    const f32x4 b1 = *(const f32x4*)(feat + (size_t)r1 * DIM + lane * 8 + 4);
    aE[0] += a0[0]; aE[1] += a0[1]; aE[2] += a0[2]; aE[3] += a0[3];
    aE[4] += b0[0]; aE[5] += b0[1]; aE[6] += b0[2]; aE[7] += b0[3];
    aO[0] += a1[0]; aO[1] += a1[1]; aO[2] += a1[2]; aO[3] += a1[3];
    aO[4] += b1[0]; aO[5] += b1[1]; aO[6] += b1[2]; aO[7] += b1[3];
  }
  if (j < cnt) {
    const int r0 = lists[w][j];
    const f32x4 a0 = *(const f32x4*)(feat + (size_t)r0 * DIM + lane * 8);
    const f32x4 b0 = *(const f32x4*)(feat + (size_t)r0 * DIM + lane * 8 + 4);
    aE[0] += a0[0]; aE[1] += a0[1]; aE[2] += a0[2]; aE[3] += a0[3];
    aE[4] += b0[0]; aE[5] += b0[1]; aE[6] += b0[2]; aE[7] += b0[3];
  }
  #pragma unroll
  for (int q = 0; q < 8; ++q) partial[w][lane * 8 + q] = aE[q] + aO[q];
  __syncthreads();

  int total = 0;
  #pragma unroll
  for (int u = 0; u < 8; ++u) total += cnts[u];
  float sv = 0.f;
  #pragma unroll
  for (int u = 0; u < 8; ++u) sv += partial[u][tid];
  psum[(size_t)(s * NCLS + c) * DIM + tid] = sv;
  if (tid == 0) pcnt[s * NCLS + c] = total;
}

// ---------------- Kernel 1b: combine segments -> row-major bf16 protos + p2 ----
__global__ __launch_bounds__(256) void k_pcomb(
    const float* __restrict__ psum, const int* __restrict__ pcnt,
    unsigned short* __restrict__ protoB, float* __restrict__ p2out)
{
  const int c = blockIdx.x;
  const int tid = threadIdx.x;
  if (c >= NCLS) {
    protoB[(size_t)c * DIM + tid] = 0;        // bf16 +0.0
    protoB[(size_t)c * DIM + 256 + tid] = 0;
    if (tid == 0) p2out[c] = 1e30f;           // never wins argmin
    return;
  }
  __shared__ float red[256];
  float a0 = 0.f, a1 = 0.f;
  int total = 0;
  #pragma unroll
  for (int s = 0; s < NSEG; ++s) {            // fixed combine order: deterministic
    a0 += psum[(size_t)(s * NCLS + c) * DIM + tid];
    a1 += psum[(size_t)(s * NCLS + c) * DIM + 256 + tid];
    total += pcnt[s * NCLS + c];
  }
  const float inv = 1.0f / ((float)total + 1e-8f);   // counts + EPS
  const float p0 = a0 * inv, p1 = a1 * inv;
  protoB[(size_t)c * DIM + tid] = (unsigned short)bf16s(p0);
  protoB[(size_t)c * DIM + 256 + tid] = (unsigned short)bf16s(p1);

  red[tid] = p0 * p0 + p1 * p1;
  __syncthreads();
  for (int st = 128; st > 0; st >>= 1) {
    if (tid < st) red[tid] += red[tid + st];
    __syncthreads();
  }
  if (tid == 0) p2out[c] = red[0];
}

// ---------------- Kernel 2: B-resident-in-LDS MFMA GEMM + argmin + loss --------
// 512 blocks x 256 thr (4 waves, 2M x 2N) = 2 blocks/CU. Block: 64 rows x 224.
// B staged ONCE per K-quarter (57KB, XOR-swizzled, conflict-free). A streams
// global->reg->bf16 with batch prefetch. Only 2 barriers per pass (8 total).
__global__ __launch_bounds__(256, 2) void k_score(
    const float* __restrict__ feat, const int* __restrict__ labels,
    const unsigned short* __restrict__ protoB, const float* __restrict__ p2,
    float* __restrict__ partials)
{
  __shared__ __align__(16) unsigned short Bs[NPADP * KQ];   // 57,344 B
  __shared__ float rd_d[2][BM];
  __shared__ int   rd_c[2][BM];
  __shared__ float rd_p[2][BM];

  const int tid = threadIdx.x;
  const int lane = tid & 63;
  const int w = tid >> 6;
  const int wm = w >> 1, wn = w & 1;
  const int lr = lane & 15;
  const int kg = lane >> 4;
  const int blockRow = blockIdx.x * BM;

  const int r0v = wm * 32 + lr;           // this lane's A rows
  const int r1v = r0v + 16;
  const float* a0p = feat + (size_t)(blockRow + r0v) * DIM;
  const float* a1p = feat + (size_t)(blockRow + r1v) * DIM;

  f32x4 acc0[NTW], acc1[NTW];
  #pragma unroll
  for (int n = 0; n < NTW; ++n) {
    acc0[n] = f32x4{0.f, 0.f, 0.f, 0.f};
    acc1[n] = f32x4{0.f, 0.f, 0.f, 0.f};
  }
  float f2a = 0.f, f2b = 0.f;

#define ASTEP(X0, X1, X2, X3)                                                    \
  do {                                                                           \
    f2a += sumsq(X0) + sumsq(X1);                                                \
    f2b += sumsq(X2) + sumsq(X3);                                                \
    const bf16x8 Af0 = pack8(X0, X1);                                            \
    const bf16x8 Af1 = pack8(X2, X3);                                            \
    _Pragma("unroll")                                                            \
    for (int n = 0; n < NTW; ++n) {                                              \
      const int row = wn * 112 + n * 16 + lr;                                    \
      const bf16x8 Bf = *(const bf16x8*)&Bs[row * KQ + (ulog ^ lr) * 8];         \
      acc0[n] = __builtin_amdgcn_mfma_f32_16x16x32_bf16(Af0, Bf, acc0[n], 0, 0, 0); \
      acc1[n] = __builtin_amdgcn_mfma_f32_16x16x32_bf16(Af1, Bf, acc1[n], 0, 0, 0); \
    }                                                                            \
  } while (0)

  for (int p = 0; p < NPASS; ++p) {
    // issue B-stage global loads (L2-resident; 14 x 16B per thread, coalesced)
    f32x4 bst[14];
    #pragma unroll
    for (int i = 0; i < 14; ++i) {
      const int u = i * 256 + tid;
      const int row = u >> 4, uin = u & 15;
      bst[i] = *(const f32x4*)(protoB + (size_t)row * DIM + p * KQ + uin * 8);
    }
    // issue A batch0 (steps 0,1) — stays in flight across the barrier
    f32x4 aP0[8];
    #pragma unroll
    for (int s = 0; s < 2; ++s) {
      const int ko = p * KQ + s * 32 + kg * 8;
      aP0[s * 4 + 0] = *(const f32x4*)(a0p + ko);
      aP0[s * 4 + 1] = *(const f32x4*)(a0p + ko + 4);
      aP0[s * 4 + 2] = *(const f32x4*)(a1p + ko);
      aP0[s * 4 + 3] = *(const f32x4*)(a1p + ko + 4);
    }
    bar_lgkm();                           // prev-pass B reads drained everywhere
    #pragma unroll
    for (int i = 0; i < 14; ++i) {        // swizzled LDS write (2-way = free)
      const int u = i * 256 + tid;
      const int row = u >> 4, uin = u & 15;
      *(f32x4*)&Bs[row * KQ + ((uin ^ (row & 15)) * 8)] = bst[i];
    }
    bar_lgkm();                           // staged B visible to all waves
    // issue A batch1 (steps 2,3) — lands during steps 0,1
    f32x4 aP1[8];
    #pragma unroll
    for (int s = 0; s < 2; ++s) {
      const int ko = p * KQ + (s + 2) * 32 + kg * 8;
      aP1[s * 4 + 0] = *(const f32x4*)(a0p + ko);
      aP1[s * 4 + 1] = *(const f32x4*)(a0p + ko + 4);
      aP1[s * 4 + 2] = *(const f32x4*)(a1p + ko);
      aP1[s * 4 + 3] = *(const f32x4*)(a1p + ko + 4);
    }
    // 4 MFMA steps, no barriers: compiler free-schedules ds_reads + MFMAs
    {
      { const int ulog = 0 * 4 + kg; ASTEP(aP0[0], aP0[1], aP0[2], aP0[3]); }
      { const int ulog = 1 * 4 + kg; ASTEP(aP0[4], aP0[5], aP0[6], aP0[7]); }
      { const int ulog = 2 * 4 + kg; ASTEP(aP1[0], aP1[1], aP1[2], aP1[3]); }
      { const int ulog = 3 * 4 + kg; ASTEP(aP1[4], aP1[5], aP1[6], aP1[7]); }
    }
  }
#undef ASTEP

  // f2: reduce kg-partials; lane srow then holds full f2 of row wm*32+srow
  f2a += __shfl_xor(f2a, 16); f2a += __shfl_xor(f2a, 32);
  f2b += __shfl_xor(f2b, 16); f2b += __shfl_xor(f2b, 32);

  float p2v[NTW];
  #pragma unroll
  for (int n = 0; n < NTW; ++n) p2v[n] = p2[wn * 112 + n * 16 + lr];

  #pragma unroll
  for (int m = 0; m < 2; ++m) {
    #pragma unroll
    for (int r = 0; r < 4; ++r) {
      const int srow = kg * 4 + r;                    // C/D row within 16-tile
      const int lrow = wm * 32 + m * 16 + srow;       // block-local sample row
      const float f2v = __shfl(m == 0 ? f2a : f2b, srow);
      const int lab = labels[blockRow + lrow];
      float bestd = 1e38f; int bestc = 1 << 30;
      float posd = -1.f;
      #pragma unroll
      for (int n = 0; n < NTW; ++n) {
        const int cidx = wn * 112 + n * 16 + lr;      // C/D col = class
        const float sc = (m == 0) ? acc0[n][r] : acc1[n][r];
        const float d2 = fmaxf(f2v + p2v[n] - 2.0f * sc, 0.0f);
        if (cidx == lab) posd = d2;
        else if (cidx < NCLS &&
                 (d2 < bestd || (d2 == bestd && cidx < bestc))) { bestd = d2; bestc = cidx; }
      }
      #pragma unroll
      for (int sft = 1; sft < 16; sft <<= 1) {        // 16-lane group reduce
        const float od = __shfl_xor(bestd, sft);
        const int   oc = __shfl_xor(bestc, sft);
        const float op = __shfl_xor(posd, sft);
        if (od < bestd || (od == bestd && oc < bestc)) { bestd = od; bestc = oc; }
        posd = fmaxf(posd, op);
      }
      if (lr == 0) {                                  // publish per-N-half result
        rd_d[wn][lrow] = bestd; rd_c[wn][lrow] = bestc; rd_p[wn][lrow] = posd;
      }
    }
  }
  __syncthreads();

  if (tid < BM) {                                     // wave 0: combine + loss
    const float d0 = rd_d[0][tid], d1 = rd_d[1][tid];
    const int   c0 = rd_c[0][tid], c1 = rd_c[1][tid];
    float bestd;
    if (d1 < d0 || (d1 == d0 && c1 < c0)) bestd = d1;
    else                                  bestd = d0;
    const float posd = fmaxf(rd_p[0][tid], rd_p[1][tid]);
    const float dap = posd, dan = bestd;
    const float dapn = dap / (dap + dan + 1e-8f);
    const float dann = dan / (dapn + dan + 1e-8f);    // sequential normalization
    float v = fmaxf(0.f, 1.5f * dapn - 0.8f * dann + 0.6f);
    #pragma unroll
    for (int sft = 1; sft < 64; sft <<= 1) v += __shfl_xor(v, sft);
    if (tid == 0) partials[blockIdx.x] = v;
  }
}

// ---------------- Kernel 3: deterministic final reduce (512 partials) ----------
__global__ __launch_bounds__(256) void k_finish(const float* __restrict__ partials,
                                                float* __restrict__ out)
{
  __shared__ float red[256];
  const int tid = threadIdx.x;
  red[tid] = partials[tid] + partials[tid + 256];
  __syncthreads();
  for (int st = 128; st > 0; st >>= 1) {
    if (tid < st) red[tid] += red[tid + st];
    __syncthreads();
  }
  if (tid == 0) out[0] = fabsf(0.2f * (red[0] / (float)NSAMP));
}

extern "C" void kernel_launch(void* const* d_in, const int* in_sizes, int n_in,
                              void* d_out, int out_size, void* d_ws, size_t ws_size,
                              hipStream_t stream) {
  const float* feat = (const float*)d_in[0];
  const int* labels = (const int*)d_in[1];
  float* out = (float*)d_out;

  char* ws = (char*)d_ws;
  unsigned short* protoB = (unsigned short*)ws;          // 224*512*2 = 229376 B
  float* p2 = (float*)(ws + 229376);                     // 224 floats (pad to 1K)
  float* partials = (float*)(ws + 230400);               // 512 floats
  float* psum = (float*)(ws + 232448);                   // 8*200*512*4 = 3276800 B
  int* pcnt = (int*)(ws + 3509248);                      // 1600 ints

  k_psum<<<NSEG * NCLS, 512, 0, stream>>>(feat, labels, psum, pcnt);
  k_pcomb<<<NPADP, 256, 0, stream>>>(psum, pcnt, protoB, p2);
  k_score<<<512, 256, 0, stream>>>(feat, labels, protoB, p2, partials);
  k_finish<<<1, 256, 0, stream>>>(partials, out);
}